// Round 9
// baseline (170.391 us; speedup 1.0000x reference)
//
#include <hip/hip_runtime.h>

// InverseBarkScale: 30-iter SGD with momentum inverting a bark filterbank.
// fb (513x128): freq f has taps only at columns (k1(f), k1(f)+1); k1 is
// monotone in f, so P(c) = {f : k1(f)=c} are contiguous and partition
// [0,513). |P(c)| <= ~3 for c<64, <= ~18 for c>=64. Rows f=0 and f=512 are
// all-zero (edge-attached with w=0 -> spec passes through).
//
// R9: kill the hidden SECOND FULL PASS. Since R2 the "repair" launch has
// been running all S iterations again (S<30 on this data: fp32 loss
// plateau trips |prev-loss|<1e-8) -- ~38us duplicated. Now iter_snap
// writes the updated spec to a per-iteration snapshot in d_ws (127MB of
// the 268MB workspace; per-lane contiguous-f chunks -> coalesced,
// fire-and-forget) and select_out copies snapshot[S-1] -> out (exact:
// output = spec after S updates = state stored at iteration S-1).
// iter core unchanged from R7/R8: all-register, lane owns cols (l,127-l)
// + their primary freqs; 4 shfl/iter latency-hidden; no LDS, no barriers.
// Setup: R8's multi-block ballot kernels (R5-R7's fused setup was a 41us
// single-CU latency chain -- never again).

#define NSTFT 513
#define NBARK 128
#define BATCH 4
#define TIME  512
#define MAXIT 30
#define NROWS (BATCH*TIME)      // 2048 rows, 1 wave each
#define SA 6                    // A-side slots (cols 0..63, max ~3 real)
#define SB 20                   // B-side slots (cols 64..127, max ~18 real)
#define ROWF 516                // snapshot row stride (513 + pad, 16B mult)

// d_ws layout (bytes); ~127.2 MB of the 268MB workspace.
#define WS_S_OFF    0                         // int: stop iteration S
#define WS_FT_OFF   256                       // float4[NSTFT]: {k1,w1,-,w2}
#define WS_HA_OFF   8464                      // int2[64]: A {fbase,cnt}
#define WS_HB_OFF   8976                      // int2[64]: B {fbase,cnt}
#define WS_WT_OFF   9488                      // float2[SA+SB][64]: {w1,w2}
#define WS_BP_OFF   22800                     // float[MAXIT][NROWS] partials
#define WS_SNAP_OFF 268800                    // float[MAXIT][NROWS][ROWF]

// ---- setup 1: per-freq taps, one wave per freq (1 load-round) ----
__global__ __launch_bounds__(64) void setup_taps(const float* __restrict__ fb,
                                                 char* __restrict__ ws) {
    const int f = blockIdx.x, lane = threadIdx.x;
    const float2 v = ((const float2*)(fb + (size_t)f * NBARK))[lane];
    unsigned long long mx = __ballot(v.x > 0.f);
    unsigned long long my = __ballot(v.y > 0.f);
    int kx = mx ? 2 * (__ffsll(mx) - 1)     : 999;
    int ky = my ? 2 * (__ffsll(my) - 1) + 1 : 999;
    int k1 = min(kx, ky);
    float w1 = 0.f, w2 = 0.f;
    if (k1 < NBARK) {
        float sx = __shfl(v.x, k1 >> 1);
        float sy = __shfl(v.y, k1 >> 1);
        w1 = (k1 & 1) ? sy : sx;
        const int k2 = k1 + 1;                   // taps are consecutive cols
        if (k2 < NBARK) {
            float tx = __shfl(v.x, k2 >> 1);
            float ty = __shfl(v.y, k2 >> 1);
            w2 = (k2 & 1) ? ty : tx;             // ==0 if row has 1 tap
        }
    } else {
        k1 = (f < 256) ? 0 : 127;                // all-zero row: edge attach
    }
    if (lane == 0) {
        float4 e;
        e.x = __int_as_float(k1); e.y = w1;
        e.z = 0.f;                e.w = w2;
        ((float4*)(ws + WS_FT_OFF))[f] = e;
    }
}

// ---- setup 2: per-column headers + packed weights, one wave per column ----
__global__ __launch_bounds__(64) void setup_lanes(char* __restrict__ ws) {
    const int c = blockIdx.x, lane = threadIdx.x;
    const float4* ftab = (const float4*)(ws + WS_FT_OFF);
    int fmin = 0x7fffffff, fmax = -1;
#pragma unroll
    for (int s = 0; s < 9; ++s) {
        int f = lane + 64*s;
        if (f < NSTFT) {
            float4 e = ftab[f];
            if (__float_as_int(e.x) == c) { fmin = min(fmin, f); fmax = max(fmax, f); }
        }
    }
#pragma unroll
    for (int m = 32; m; m >>= 1) {
        fmin = min(fmin, __shfl_xor(fmin, m));
        fmax = max(fmax, __shfl_xor(fmax, m));
    }
    int cnt = (fmax >= 0) ? (fmax - fmin + 1) : 0;
    if (fmax < 0) fmin = 0;
    const int cap  = (c < 64) ? SA : SB;
    const int base = (c < 64) ? 0  : SA;
    const int lf   = (c < 64) ? c  : 127 - c;
    cnt = min(cnt, cap);
    if (lane == 0)
        ((int2*)(ws + (c < 64 ? WS_HA_OFF : WS_HB_OFF)))[lf] =
            make_int2(fmin, cnt);
    if (lane < cap) {
        float2 wv = make_float2(0.f, 0.f);
        if (lane < cnt) {
            float4 e = ftab[fmin + lane];        // L2-hit re-read, tiny
            wv = make_float2(e.y, e.w);
        }
        ((float2*)(ws + WS_WT_OFF))[(base + lane)*64 + lf] = wv;
    }
}

__global__ __launch_bounds__(64, 2) void
iter_snap(const float* __restrict__ barkspec,
          const float* __restrict__ spec_init,
          char* __restrict__ ws)
{
    const int lane = threadIdx.x;            // single wave per block, no LDS

    const int r     = blockIdx.x;
    const int batch = r >> 9;
    const int t     = r & (TIME - 1);

    // ---- per-lane tables -> registers ----
    const int2 hA = ((const int2*)(ws + WS_HA_OFF))[lane];
    const int2 hB = ((const int2*)(ws + WS_HB_OFF))[lane];
    const float2* wt = (const float2*)(ws + WS_WT_OFF);
    const float* spg = spec_init + ((size_t)batch*TIME + t)*NSTFT;

    float w1A[SA], w2A[SA], spA[SA], bfA[SA];
    float w1B[SB], w2B[SB], spB[SB], bfB[SB];
#pragma unroll
    for (int i = 0; i < SA; ++i) {
        float2 v = wt[i*64 + lane];
        w1A[i] = v.x; w2A[i] = v.y;
        spA[i] = (i < hA.y) ? spg[hA.x + i] : 0.f;
        bfA[i] = 0.f;
    }
#pragma unroll
    for (int i = 0; i < SB; ++i) {
        float2 v = wt[(SA + i)*64 + lane];
        w1B[i] = v.x; w2B[i] = v.y;
        spB[i] = (i < hB.y) ? spg[hB.x + i] : 0.f;
        bfB[i] = 0.f;
    }

    const float* bs = barkspec + (size_t)batch*NBARK*TIME + t;
    const float m0 = bs[(size_t)lane*TIME];          // col cA = lane
    const float m1 = bs[(size_t)(127 - lane)*TIME];  // col cB = 127-lane

    float* bp = (float*)(ws + WS_BP_OFF);
    // snapshot chunk pointers for this lane (contiguous freqs)
    float* snA = (float*)(ws + WS_SNAP_OFF) + (size_t)r*ROWF + hA.x;
    float* snB = (float*)(ws + WS_SNAP_OFF) + (size_t)r*ROWF + hB.x;
    const size_t SNAP_IT = (size_t)NROWS * ROWF;     // floats per iteration

    const float GC = -2.0f / (float)NROWS;
    float lp_prev = 0.f;                     // loss partial of iteration it-1

    for (int it = 0; it < MAXIT; ++it) {
        // ---- forward, carry-producing sums FIRST; issue their shfls early
        float sBA = 0.f, sBB = 0.f;
#pragma unroll
        for (int i = 0; i < SA; ++i) sBA = fmaf(spA[i], w2A[i], sBA);
#pragma unroll
        for (int i = 0; i < SB; ++i) sBB = fmaf(spB[i], w2B[i], sBB);
        float cAin = __shfl_up(sBA, 1);      // latency hidden under sAA/sAB
        float cBin = __shfl_down(sBB, 1);

        // ---- deferred loss reduction of iter it-1 (independent of iter it)
        if (it > 0) {
            float lp = lp_prev;
#pragma unroll
            for (int m = 32; m; m >>= 1) lp += __shfl_xor(lp, m);
            if (lane == 0) bp[(it - 1)*NROWS + r] = lp;  // fire-and-forget
        }

        float sAA = 0.f, sAB = 0.f;
#pragma unroll
        for (int i = 0; i < SA; ++i) sAA = fmaf(spA[i], w1A[i], sAA);
#pragma unroll
        for (int i = 0; i < SB; ++i) sAB = fmaf(spB[i], w1B[i], sAB);

        if (lane == 0)  cAin = 0.f;
        if (lane == 63) cBin = sBA;
        const float d0 = m0 - (sAA + cAin);
        const float d1 = m1 - (sAB + cBin);
        lp_prev = fmaf(d0, d0, d1*d1);

        // ---- backward; dAn/dBn latency hidden under momentum decay
        float dAn = __shfl_down(d0, 1);
        float dBn = __shfl_up(d1, 1);        // lane0: its w2B are all 0
        const float g0 = GC * d0, g1 = GC * d1;
#pragma unroll
        for (int i = 0; i < SA; ++i) bfA[i] *= 0.9f;   // indep of shfls
#pragma unroll
        for (int i = 0; i < SB; ++i) bfB[i] *= 0.9f;
        if (lane == 63) dAn = d1;
        const float gA = GC * dAn, gB = GC * dBn;
#pragma unroll
        for (int i = 0; i < SA; ++i) {
            float g = fmaf(g0, w1A[i], gA * w2A[i]);
            bfA[i] += g;
            float v = fmaf(-0.1f, bfA[i], spA[i]);
            spA[i] = v < 0.f ? 0.f : v;
        }
#pragma unroll
        for (int i = 0; i < SB; ++i) {
            float g = fmaf(g1, w1B[i], gB * w2B[i]);
            bfB[i] += g;
            float v = fmaf(-0.1f, bfB[i], spB[i]);
            spB[i] = v < 0.f ? 0.f : v;
        }

        // ---- snapshot this iteration's state (coalesced: wave covers the
        //      whole 516-float row via per-lane contiguous chunks)
#pragma unroll
        for (int i = 0; i < SA; ++i)
            if (i < hA.y) snA[i] = spA[i];
#pragma unroll
        for (int i = 0; i < SB; ++i)
            if (i < hB.y) snB[i] = spB[i];
        snA += SNAP_IT; snB += SNAP_IT;
    }

    // ---- flush last iteration's loss partial
    {
        float lp = lp_prev;
#pragma unroll
        for (int m = 32; m; m >>= 1) lp += __shfl_xor(lp, m);
        if (lane == 0) bp[(MAXIT - 1)*NROWS + r] = lp;
    }
}

// ---- scan: 16 waves, one iteration each (coalesced float4) + stop logic ----
__global__ __launch_bounds__(1024) void scan_all(char* __restrict__ ws) {
    __shared__ float losses[MAXIT];
    const int tid = threadIdx.x, wave = tid >> 6, lane = tid & 63;
    const float* bp = (const float*)(ws + WS_BP_OFF);
    for (int it = wave; it < MAXIT; it += 16) {
        const float4* b4 = (const float4*)(bp + (size_t)it*NROWS);
        float s = 0.f;
#pragma unroll
        for (int j = 0; j < NROWS/256; ++j) {      // 8 x float4 per lane
            float4 v = b4[j*64 + lane];
            s += (v.x + v.y) + (v.z + v.w);
        }
#pragma unroll
        for (int m = 32; m; m >>= 1) s += __shfl_xor(s, m);
        if (lane == 0) losses[it] = s * (1.0f/(float)NROWS);
    }
    __syncthreads();
    if (tid == 0) {
        // reference stop logic: update applied on the stop iteration,
        // frozen after -> S = first stop index + 1, else MAXIT
        float prev = __builtin_inff();
        int S = MAXIT;
        for (int i = 0; i < MAXIT; ++i) {
            float l = losses[i];
            if (l < 1e-5f || fabsf(prev - l) < 1e-8f) { S = i + 1; break; }
            prev = l;
        }
        *(int*)(ws + WS_S_OFF) = S;
    }
}

// ---- select: out[b,f,t] = snapshot[S-1][b*512+t][f] ----
// block = (batch, 4-freq group); lane = t offset; float4 read covers 4 f's,
// 4 coalesced 256B t-row writes. No transpose needed: lane already holds
// the 4 values for its t.
__global__ __launch_bounds__(64) void select_out(const char* __restrict__ ws,
                                                 float* __restrict__ out) {
    const int lane = threadIdx.x;
    const int S = *(const int*)(ws + WS_S_OFF);
    const float* snap = (const float*)(ws + WS_SNAP_OFF)
                      + (size_t)(S - 1) * NROWS * ROWF;
    const int b  = blockIdx.x / 129;             // 129 groups of 4 freqs
    const int f0 = (blockIdx.x % 129) * 4;
    float* og = out + ((size_t)b*NSTFT + f0)*TIME;
    for (int t0 = 0; t0 < TIME; t0 += 64) {
        const int t = t0 + lane;
        const int r = (b << 9) | t;
        float4 v = *(const float4*)(snap + (size_t)r*ROWF + f0); // 16B aligned
        og[t] = v.x;                                  // f0   < 513 always
        if (f0 + 1 < NSTFT) og[(size_t)TIME   + t] = v.y;
        if (f0 + 2 < NSTFT) og[(size_t)2*TIME + t] = v.z;
        if (f0 + 3 < NSTFT) og[(size_t)3*TIME + t] = v.w;
    }
}

extern "C" void kernel_launch(void* const* d_in, const int* in_sizes, int n_in,
                              void* d_out, int out_size, void* d_ws, size_t ws_size,
                              hipStream_t stream)
{
    const float* barkspec  = (const float*)d_in[0];
    const float* fb        = (const float*)d_in[1];
    const float* spec_init = (const float*)d_in[2];
    float* out = (float*)d_out;
    char* ws = (char*)d_ws;

    setup_taps <<<NSTFT, 64, 0, stream>>>(fb, ws);
    setup_lanes<<<NBARK, 64, 0, stream>>>(ws);
    iter_snap  <<<NROWS, 64, 0, stream>>>(barkspec, spec_init, ws);
    scan_all   <<<1, 1024, 0, stream>>>(ws);
    select_out <<<BATCH*129, 64, 0, stream>>>(ws, out);
}

// Round 10
// 121.200 us; speedup vs baseline: 1.4059x; 1.4059x over previous
//
#include <hip/hip_runtime.h>

// InverseBarkScale: 30-iter SGD with momentum inverting a bark filterbank.
// fb (513x128): freq f has taps only at columns (k1(f), k1(f)+1); k1 is
// monotone in f, so P(c) = {f : k1(f)=c} are contiguous and partition
// [0,513). |P(c)| <= ~4 for c<64, <= ~18 for c>=64.
//
// R10: R9's full per-iteration snapshot regressed (+60us): per-lane-chunk
// stores put ~33 cache lines under EACH wave-store instruction (address
// dispersion, ~1 line-transaction/cycle/CU). Fix = CHECKPOINTS, not
// snapshots: store spec+buf at it=8/16/24 in SLOT-MAJOR layout
// (addr = slot*64+lane -> 256B contiguous per store, 4 lines/instr).
// 82MB coalesced total. Repair then replays only S-base <= 7 iterations
// from the nearest checkpoint (R6 evidence: S~29, so old repair was a
// full 2nd pass, ~38us). Out is written only by repair (always runs).
//  - iter core: R7/R8 proven (all-register, lane owns cols (l,127-l) +
//    their primary freqs; 4 shfl/iter latency-hidden; no LDS/barriers).
//  - setup: R8 multi-block ballot kernels (fused single-block setup was a
//    41us single-CU latency chain -- never again).
// Checkpoint exactness: register pads are 0, stored/reloaded as 0; fp32
// state -> replay bit-identical to continuing.

#define NSTFT 513
#define NBARK 128
#define BATCH 4
#define TIME  512
#define MAXIT 30
#define NROWS (BATCH*TIME)      // 2048 rows, 1 wave each
#define SA 6                    // A-side slots (cols 0..63, max ~4 real)
#define SB 20                   // B-side slots (cols 64..127, max ~18 real)
#define CPF  ((SA+SB)*64)       // 1664 floats per slot-major cp row

// d_ws layout (bytes); ~82.3 MB of the 268MB workspace.
#define WS_S_OFF   0                          // int: stop iteration S
#define WS_FT_OFF  256                        // float4[NSTFT]: {k1,w1,-,w2}
#define WS_HA_OFF  8464                       // int2[64]: A {fbase,cnt}
#define WS_HB_OFF  8976                       // int2[64]: B {fbase,cnt}
#define WS_WT_OFF  9488                       // float2[SA+SB][64]: {w1,w2}
#define WS_BP_OFF  22800                      // float[MAXIT][NROWS] partials
#define WS_CP_OFF  268800                     // float[3][2][NROWS][CPF]

// ---- setup 1: per-freq taps, one wave per freq (1 load-round) ----
__global__ __launch_bounds__(64) void setup_taps(const float* __restrict__ fb,
                                                 char* __restrict__ ws) {
    const int f = blockIdx.x, lane = threadIdx.x;
    const float2 v = ((const float2*)(fb + (size_t)f * NBARK))[lane];
    unsigned long long mx = __ballot(v.x > 0.f);
    unsigned long long my = __ballot(v.y > 0.f);
    int kx = mx ? 2 * (__ffsll(mx) - 1)     : 999;
    int ky = my ? 2 * (__ffsll(my) - 1) + 1 : 999;
    int k1 = min(kx, ky);
    float w1 = 0.f, w2 = 0.f;
    if (k1 < NBARK) {
        float sx = __shfl(v.x, k1 >> 1);
        float sy = __shfl(v.y, k1 >> 1);
        w1 = (k1 & 1) ? sy : sx;
        const int k2 = k1 + 1;                   // taps are consecutive cols
        if (k2 < NBARK) {
            float tx = __shfl(v.x, k2 >> 1);
            float ty = __shfl(v.y, k2 >> 1);
            w2 = (k2 & 1) ? ty : tx;             // ==0 if row has 1 tap
        }
    } else {
        k1 = (f < 256) ? 0 : 127;                // all-zero row: edge attach
    }
    if (lane == 0) {
        float4 e;
        e.x = __int_as_float(k1); e.y = w1;
        e.z = 0.f;                e.w = w2;
        ((float4*)(ws + WS_FT_OFF))[f] = e;
    }
}

// ---- setup 2: per-column headers + packed weights, one wave per column ----
__global__ __launch_bounds__(64) void setup_lanes(char* __restrict__ ws) {
    const int c = blockIdx.x, lane = threadIdx.x;
    const float4* ftab = (const float4*)(ws + WS_FT_OFF);
    int fmin = 0x7fffffff, fmax = -1;
#pragma unroll
    for (int s = 0; s < 9; ++s) {
        int f = lane + 64*s;
        if (f < NSTFT) {
            float4 e = ftab[f];
            if (__float_as_int(e.x) == c) { fmin = min(fmin, f); fmax = max(fmax, f); }
        }
    }
#pragma unroll
    for (int m = 32; m; m >>= 1) {
        fmin = min(fmin, __shfl_xor(fmin, m));
        fmax = max(fmax, __shfl_xor(fmax, m));
    }
    int cnt = (fmax >= 0) ? (fmax - fmin + 1) : 0;
    if (fmax < 0) fmin = 0;
    const int cap  = (c < 64) ? SA : SB;
    const int base = (c < 64) ? 0  : SA;
    const int lf   = (c < 64) ? c  : 127 - c;
    cnt = min(cnt, cap);
    if (lane == 0)
        ((int2*)(ws + (c < 64 ? WS_HA_OFF : WS_HB_OFF)))[lf] =
            make_int2(fmin, cnt);
    if (lane < cap) {
        float2 wv = make_float2(0.f, 0.f);
        if (lane < cnt) {
            float4 e = ftab[fmin + lane];        // L2-hit re-read, tiny
            wv = make_float2(e.y, e.w);
        }
        ((float2*)(ws + WS_WT_OFF))[(base + lane)*64 + lf] = wv;
    }
}

__global__ __launch_bounds__(64, 2) void
iter_cp(const float* __restrict__ barkspec,
        const float* __restrict__ spec_init,
        char* __restrict__ ws)
{
    const int lane = threadIdx.x;            // single wave per block, no LDS
    const int r     = blockIdx.x;
    const int batch = r >> 9;
    const int t     = r & (TIME - 1);

    // ---- per-lane tables -> registers ----
    const int2 hA = ((const int2*)(ws + WS_HA_OFF))[lane];
    const int2 hB = ((const int2*)(ws + WS_HB_OFF))[lane];
    const float2* wt = (const float2*)(ws + WS_WT_OFF);
    const float* spg = spec_init + ((size_t)batch*TIME + t)*NSTFT;

    float w1A[SA], w2A[SA], spA[SA], bfA[SA];
    float w1B[SB], w2B[SB], spB[SB], bfB[SB];
#pragma unroll
    for (int i = 0; i < SA; ++i) {
        float2 v = wt[i*64 + lane];
        w1A[i] = v.x; w2A[i] = v.y;
        spA[i] = (i < hA.y) ? spg[hA.x + i] : 0.f;
        bfA[i] = 0.f;
    }
#pragma unroll
    for (int i = 0; i < SB; ++i) {
        float2 v = wt[(SA + i)*64 + lane];
        w1B[i] = v.x; w2B[i] = v.y;
        spB[i] = (i < hB.y) ? spg[hB.x + i] : 0.f;
        bfB[i] = 0.f;
    }

    const float* bs = barkspec + (size_t)batch*NBARK*TIME + t;
    const float m0 = bs[(size_t)lane*TIME];          // col cA = lane
    const float m1 = bs[(size_t)(127 - lane)*TIME];  // col cB = 127-lane

    float* bp = (float*)(ws + WS_BP_OFF);
    float* cp = (float*)(ws + WS_CP_OFF);
    const float GC = -2.0f / (float)NROWS;
    float lp_prev = 0.f;

    for (int it = 0; it < MAXIT; ++it) {
        // ---- forward, carry-producing sums FIRST; issue their shfls early
        float sBA = 0.f, sBB = 0.f;
#pragma unroll
        for (int i = 0; i < SA; ++i) sBA = fmaf(spA[i], w2A[i], sBA);
#pragma unroll
        for (int i = 0; i < SB; ++i) sBB = fmaf(spB[i], w2B[i], sBB);
        float cAin = __shfl_up(sBA, 1);      // latency hidden under sAA/sAB
        float cBin = __shfl_down(sBB, 1);

        // ---- deferred loss reduction of iter it-1 (independent of iter it)
        if (it > 0) {
            float lp = lp_prev;
#pragma unroll
            for (int m = 32; m; m >>= 1) lp += __shfl_xor(lp, m);
            if (lane == 0) bp[(it - 1)*NROWS + r] = lp;  // fire-and-forget
        }

        float sAA = 0.f, sAB = 0.f;
#pragma unroll
        for (int i = 0; i < SA; ++i) sAA = fmaf(spA[i], w1A[i], sAA);
#pragma unroll
        for (int i = 0; i < SB; ++i) sAB = fmaf(spB[i], w1B[i], sAB);

        if (lane == 0)  cAin = 0.f;
        if (lane == 63) cBin = sBA;
        const float d0 = m0 - (sAA + cAin);
        const float d1 = m1 - (sAB + cBin);
        lp_prev = fmaf(d0, d0, d1*d1);

        // ---- backward; dAn/dBn latency hidden under momentum decay
        float dAn = __shfl_down(d0, 1);
        float dBn = __shfl_up(d1, 1);        // lane0: its w2B are all 0
        const float g0 = GC * d0, g1 = GC * d1;
#pragma unroll
        for (int i = 0; i < SA; ++i) bfA[i] *= 0.9f;   // indep of shfls
#pragma unroll
        for (int i = 0; i < SB; ++i) bfB[i] *= 0.9f;
        if (lane == 63) dAn = d1;
        const float gA = GC * dAn, gB = GC * dBn;
#pragma unroll
        for (int i = 0; i < SA; ++i) {
            float g = fmaf(g0, w1A[i], gA * w2A[i]);
            bfA[i] += g;
            float v = fmaf(-0.1f, bfA[i], spA[i]);
            spA[i] = v < 0.f ? 0.f : v;
        }
#pragma unroll
        for (int i = 0; i < SB; ++i) {
            float g = fmaf(g1, w1B[i], gB * w2B[i]);
            bfB[i] += g;
            float v = fmaf(-0.1f, bfB[i], spB[i]);
            spB[i] = v < 0.f ? 0.f : v;
        }

        // ---- checkpoint after update 8/16/24 (it = 7/15/23), slot-major:
        //      every store is lane-contiguous 256B (4 lines/instr).
        if (it == 7 || it == 15 || it == 23) {
            const int c = it >> 3;           // 0,1,2
            float* cs = cp + ((size_t)(c*2 + 0)*NROWS + r)*CPF + lane;
            float* cb = cp + ((size_t)(c*2 + 1)*NROWS + r)*CPF + lane;
#pragma unroll
            for (int i = 0; i < SA; ++i) {
                cs[i*64] = spA[i];  cb[i*64] = bfA[i];
            }
#pragma unroll
            for (int i = 0; i < SB; ++i) {
                cs[(SA + i)*64] = spB[i];  cb[(SA + i)*64] = bfB[i];
            }
        }
    }

    // ---- flush last iteration's loss partial
    {
        float lp = lp_prev;
#pragma unroll
        for (int m = 32; m; m >>= 1) lp += __shfl_xor(lp, m);
        if (lane == 0) bp[(MAXIT - 1)*NROWS + r] = lp;
    }
}

// ---- scan: 16 waves, one iteration each (coalesced float4) + stop logic ----
__global__ __launch_bounds__(1024) void scan_all(char* __restrict__ ws) {
    __shared__ float losses[MAXIT];
    const int tid = threadIdx.x, wave = tid >> 6, lane = tid & 63;
    const float* bp = (const float*)(ws + WS_BP_OFF);
    for (int it = wave; it < MAXIT; it += 16) {
        const float4* b4 = (const float4*)(bp + (size_t)it*NROWS);
        float s = 0.f;
#pragma unroll
        for (int j = 0; j < NROWS/256; ++j) {      // 8 x float4 per lane
            float4 v = b4[j*64 + lane];
            s += (v.x + v.y) + (v.z + v.w);
        }
#pragma unroll
        for (int m = 32; m; m >>= 1) s += __shfl_xor(s, m);
        if (lane == 0) losses[it] = s * (1.0f/(float)NROWS);
    }
    __syncthreads();
    if (tid == 0) {
        // reference stop logic: update applied on the stop iteration,
        // frozen after -> S = first stop index + 1, else MAXIT
        float prev = __builtin_inff();
        int S = MAXIT;
        for (int i = 0; i < MAXIT; ++i) {
            float l = losses[i];
            if (l < 1e-5f || fabsf(prev - l) < 1e-8f) { S = i + 1; break; }
            prev = l;
        }
        *(int*)(ws + WS_S_OFF) = S;
    }
}

// ---- repair: resume from nearest checkpoint, replay <=7 iters, write out ---
__global__ __launch_bounds__(64) void
repair_out(const float* __restrict__ barkspec,
           const float* __restrict__ spec_init,
           float* __restrict__ out,
           const char* __restrict__ ws)
{
    const int lane = threadIdx.x;
    const int r     = blockIdx.x;
    const int batch = r >> 9;
    const int t     = r & (TIME - 1);

    const int S    = *(const int*)(ws + WS_S_OFF);
    const int base = (S >= 24) ? 24 : (S >= 16) ? 16 : (S >= 8) ? 8 : 0;
    const int R    = S - base;                   // 0..7 iterations to replay

    const int2 hA = ((const int2*)(ws + WS_HA_OFF))[lane];
    const int2 hB = ((const int2*)(ws + WS_HB_OFF))[lane];
    const float2* wt = (const float2*)(ws + WS_WT_OFF);

    float w1A[SA], w2A[SA], spA[SA], bfA[SA];
    float w1B[SB], w2B[SB], spB[SB], bfB[SB];
#pragma unroll
    for (int i = 0; i < SA; ++i) {
        float2 v = wt[i*64 + lane];
        w1A[i] = v.x; w2A[i] = v.y;
    }
#pragma unroll
    for (int i = 0; i < SB; ++i) {
        float2 v = wt[(SA + i)*64 + lane];
        w1B[i] = v.x; w2B[i] = v.y;
    }

    if (base == 0) {
        const float* spg = spec_init + ((size_t)batch*TIME + t)*NSTFT;
#pragma unroll
        for (int i = 0; i < SA; ++i) {
            spA[i] = (i < hA.y) ? spg[hA.x + i] : 0.f;  bfA[i] = 0.f;
        }
#pragma unroll
        for (int i = 0; i < SB; ++i) {
            spB[i] = (i < hB.y) ? spg[hB.x + i] : 0.f;  bfB[i] = 0.f;
        }
    } else {
        const int c = (base >> 3) - 1;               // 0,1,2
        const float* cp = (const float*)(ws + WS_CP_OFF);
        const float* cs = cp + ((size_t)(c*2 + 0)*NROWS + r)*CPF + lane;
        const float* cb = cp + ((size_t)(c*2 + 1)*NROWS + r)*CPF + lane;
#pragma unroll
        for (int i = 0; i < SA; ++i) {
            spA[i] = cs[i*64];  bfA[i] = cb[i*64];
        }
#pragma unroll
        for (int i = 0; i < SB; ++i) {
            spB[i] = cs[(SA + i)*64];  bfB[i] = cb[(SA + i)*64];
        }
    }

    const float* bs = barkspec + (size_t)batch*NBARK*TIME + t;
    const float m0 = bs[(size_t)lane*TIME];
    const float m1 = bs[(size_t)(127 - lane)*TIME];
    const float GC = -2.0f / (float)NROWS;

    for (int it = 0; it < R; ++it) {
        float sBA = 0.f, sBB = 0.f;
#pragma unroll
        for (int i = 0; i < SA; ++i) sBA = fmaf(spA[i], w2A[i], sBA);
#pragma unroll
        for (int i = 0; i < SB; ++i) sBB = fmaf(spB[i], w2B[i], sBB);
        float cAin = __shfl_up(sBA, 1);
        float cBin = __shfl_down(sBB, 1);

        float sAA = 0.f, sAB = 0.f;
#pragma unroll
        for (int i = 0; i < SA; ++i) sAA = fmaf(spA[i], w1A[i], sAA);
#pragma unroll
        for (int i = 0; i < SB; ++i) sAB = fmaf(spB[i], w1B[i], sAB);

        if (lane == 0)  cAin = 0.f;
        if (lane == 63) cBin = sBA;
        const float d0 = m0 - (sAA + cAin);
        const float d1 = m1 - (sAB + cBin);

        float dAn = __shfl_down(d0, 1);
        float dBn = __shfl_up(d1, 1);
        const float g0 = GC * d0, g1 = GC * d1;
#pragma unroll
        for (int i = 0; i < SA; ++i) bfA[i] *= 0.9f;
#pragma unroll
        for (int i = 0; i < SB; ++i) bfB[i] *= 0.9f;
        if (lane == 63) dAn = d1;
        const float gA = GC * dAn, gB = GC * dBn;
#pragma unroll
        for (int i = 0; i < SA; ++i) {
            float g = fmaf(g0, w1A[i], gA * w2A[i]);
            bfA[i] += g;
            float v = fmaf(-0.1f, bfA[i], spA[i]);
            spA[i] = v < 0.f ? 0.f : v;
        }
#pragma unroll
        for (int i = 0; i < SB; ++i) {
            float g = fmaf(g1, w1B[i], gB * w2B[i]);
            bfB[i] += g;
            float v = fmaf(-0.1f, bfB[i], spB[i]);
            spB[i] = v < 0.f ? 0.f : v;
        }
    }

    // ---- store out[batch, f, t] (one-time scatter; L2 merges lines)
    float* og = out + ((size_t)batch*NSTFT)*TIME + t;
#pragma unroll
    for (int i = 0; i < SA; ++i)
        if (i < hA.y) og[(size_t)(hA.x + i)*TIME] = spA[i];
#pragma unroll
    for (int i = 0; i < SB; ++i)
        if (i < hB.y) og[(size_t)(hB.x + i)*TIME] = spB[i];
}

extern "C" void kernel_launch(void* const* d_in, const int* in_sizes, int n_in,
                              void* d_out, int out_size, void* d_ws, size_t ws_size,
                              hipStream_t stream)
{
    const float* barkspec  = (const float*)d_in[0];
    const float* fb        = (const float*)d_in[1];
    const float* spec_init = (const float*)d_in[2];
    float* out = (float*)d_out;
    char* ws = (char*)d_ws;

    setup_taps <<<NSTFT, 64, 0, stream>>>(fb, ws);
    setup_lanes<<<NBARK, 64, 0, stream>>>(ws);
    iter_cp    <<<NROWS, 64, 0, stream>>>(barkspec, spec_init, ws);
    scan_all   <<<1, 1024, 0, stream>>>(ws);
    repair_out <<<NROWS, 64, 0, stream>>>(barkspec, spec_init, out, ws);
}

// Round 11
// 109.265 us; speedup vs baseline: 1.5594x; 1.1092x over previous
//
#include <hip/hip_runtime.h>

// InverseBarkScale: 30-iter SGD with momentum inverting a bark filterbank.
// fb (513x128): freq f has taps only at columns (k1(f), k1(f)+1); k1 is
// monotone in f, so P(c) = {f : k1(f)=c} are contiguous and partition
// [0,513). |P(c)| <= ~4 for c<64, <= ~18 for c>=64.
//
// R11: launch-sum reconciliation across R6-R10 shows S == 30 on this data
// (R8's 104.9 only closes with an immediate-exit repair; R6's 42us "repair"
// rows were mode0 rows from a second PMC replay pass -- WRITE_SIZE=NaN was
// the tell). So: revert R9/R10's snapshot/checkpoint machinery (pure
// overhead) to R8's speculate + immediate-exit repair, and attack iter's
// stalls instead:
//  - DELETE the in-kernel 6-round shfl loss reduction (6 of 10 DS-permute
//    rounds/iter, serially dependent): store the PER-LANE partial d0^2+d1^2
//    (one coalesced 256B store/iter, fire-and-forget); a 30-block
//    scan_reduce does the 64-way reduction; repair computes S inline from
//    losses[30] (no extra launch).
//  - split the 20-deep sAB/sBB fmaf chains into 2x10 partials (dep latency
//    80 -> 40 cyc).
// iter core otherwise R7/R8: all-register, lane owns cols (l,127-l) + their
// primary freqs, 4 shfl-by-+-1 per iter, no LDS, no barriers.
// Setup: R8 multi-block ballot kernels (single-block fused setup was a 41us
// one-CU latency chain -- never again).

#define NSTFT 513
#define NBARK 128
#define BATCH 4
#define TIME  512
#define MAXIT 30
#define NROWS (BATCH*TIME)      // 2048 rows, 1 wave each
#define SA 6                    // A-side slots (cols 0..63, max ~4 real)
#define SB 20                   // B-side slots (cols 64..127, max ~18 real)

// d_ws layout (bytes); ~15.8 MB used. Every field written before read.
#define WS_L_OFF   16                         // float[MAXIT]: losses
#define WS_FT_OFF  256                        // float4[NSTFT]: {k1,w1,-,w2}
#define WS_HA_OFF  8464                       // int2[64]: A {fbase,cnt}
#define WS_HB_OFF  8976                       // int2[64]: B {fbase,cnt}
#define WS_WT_OFF  9488                       // float2[SA+SB][64]: {w1,w2}
#define WS_BP_OFF  22848                      // float[MAXIT][NROWS][64]

// ---- setup 1: per-freq taps, one wave per freq (1 load-round) ----
__global__ __launch_bounds__(64) void setup_taps(const float* __restrict__ fb,
                                                 char* __restrict__ ws) {
    const int f = blockIdx.x, lane = threadIdx.x;
    const float2 v = ((const float2*)(fb + (size_t)f * NBARK))[lane];
    unsigned long long mx = __ballot(v.x > 0.f);
    unsigned long long my = __ballot(v.y > 0.f);
    int kx = mx ? 2 * (__ffsll(mx) - 1)     : 999;
    int ky = my ? 2 * (__ffsll(my) - 1) + 1 : 999;
    int k1 = min(kx, ky);
    float w1 = 0.f, w2 = 0.f;
    if (k1 < NBARK) {
        float sx = __shfl(v.x, k1 >> 1);
        float sy = __shfl(v.y, k1 >> 1);
        w1 = (k1 & 1) ? sy : sx;
        const int k2 = k1 + 1;                   // taps are consecutive cols
        if (k2 < NBARK) {
            float tx = __shfl(v.x, k2 >> 1);
            float ty = __shfl(v.y, k2 >> 1);
            w2 = (k2 & 1) ? ty : tx;             // ==0 if row has 1 tap
        }
    } else {
        k1 = (f < 256) ? 0 : 127;                // all-zero row: edge attach
    }
    if (lane == 0) {
        float4 e;
        e.x = __int_as_float(k1); e.y = w1;
        e.z = 0.f;                e.w = w2;
        ((float4*)(ws + WS_FT_OFF))[f] = e;
    }
}

// ---- setup 2: per-column headers + packed weights, one wave per column ----
__global__ __launch_bounds__(64) void setup_lanes(char* __restrict__ ws) {
    const int c = blockIdx.x, lane = threadIdx.x;
    const float4* ftab = (const float4*)(ws + WS_FT_OFF);
    int fmin = 0x7fffffff, fmax = -1;
#pragma unroll
    for (int s = 0; s < 9; ++s) {
        int f = lane + 64*s;
        if (f < NSTFT) {
            float4 e = ftab[f];
            if (__float_as_int(e.x) == c) { fmin = min(fmin, f); fmax = max(fmax, f); }
        }
    }
#pragma unroll
    for (int m = 32; m; m >>= 1) {
        fmin = min(fmin, __shfl_xor(fmin, m));
        fmax = max(fmax, __shfl_xor(fmax, m));
    }
    int cnt = (fmax >= 0) ? (fmax - fmin + 1) : 0;
    if (fmax < 0) fmin = 0;
    const int cap  = (c < 64) ? SA : SB;
    const int base = (c < 64) ? 0  : SA;
    const int lf   = (c < 64) ? c  : 127 - c;
    cnt = min(cnt, cap);
    if (lane == 0)
        ((int2*)(ws + (c < 64 ? WS_HA_OFF : WS_HB_OFF)))[lf] =
            make_int2(fmin, cnt);
    if (lane < cap) {
        float2 wv = make_float2(0.f, 0.f);
        if (lane < cnt) {
            float4 e = ftab[fmin + lane];        // L2-hit re-read, tiny
            wv = make_float2(e.y, e.w);
        }
        ((float2*)(ws + WS_WT_OFF))[(base + lane)*64 + lf] = wv;
    }
}

__global__ __launch_bounds__(64, 2) void
iter_kernel(const float* __restrict__ barkspec,
            const float* __restrict__ spec_init,
            float* __restrict__ out,
            char* __restrict__ ws, int mode)
{
    const int lane = threadIdx.x;            // single wave per block, no LDS

    int niter = MAXIT;
    if (mode) {
        // reference stop logic from losses[]: update applied on the stop
        // iteration, frozen after -> S = first stop index + 1, else MAXIT
        const float* losses = (const float*)(ws + WS_L_OFF);
        float prev = __builtin_inff();
        int S = MAXIT;
        for (int i = 0; i < MAXIT; ++i) {
            float l = losses[i];
            if (l < 1e-5f || fabsf(prev - l) < 1e-8f) { S = i + 1; break; }
            prev = l;
        }
        if (S >= MAXIT) return;              // expected path: no repair
        niter = S;
    }

    const int r     = blockIdx.x;
    const int batch = r >> 9;
    const int t     = r & (TIME - 1);

    // ---- per-lane tables -> registers ----
    const int2 hA = ((const int2*)(ws + WS_HA_OFF))[lane];
    const int2 hB = ((const int2*)(ws + WS_HB_OFF))[lane];
    const float2* wt = (const float2*)(ws + WS_WT_OFF);
    const float* spg = spec_init + ((size_t)batch*TIME + t)*NSTFT;

    float w1A[SA], w2A[SA], spA[SA], bfA[SA];
    float w1B[SB], w2B[SB], spB[SB], bfB[SB];
#pragma unroll
    for (int i = 0; i < SA; ++i) {
        float2 v = wt[i*64 + lane];
        w1A[i] = v.x; w2A[i] = v.y;
        spA[i] = (i < hA.y) ? spg[hA.x + i] : 0.f;
        bfA[i] = 0.f;
    }
#pragma unroll
    for (int i = 0; i < SB; ++i) {
        float2 v = wt[(SA + i)*64 + lane];
        w1B[i] = v.x; w2B[i] = v.y;
        spB[i] = (i < hB.y) ? spg[hB.x + i] : 0.f;
        bfB[i] = 0.f;
    }

    const float* bs = barkspec + (size_t)batch*NBARK*TIME + t;
    const float m0 = bs[(size_t)lane*TIME];          // col cA = lane
    const float m1 = bs[(size_t)(127 - lane)*TIME];  // col cB = 127-lane

    // per-lane loss partial store target (256B coalesced per wave)
    float* bpL = (float*)(ws + WS_BP_OFF) + (size_t)r*64 + lane;
    const float GC = -2.0f / (float)NROWS;

    for (int it = 0; it < niter; ++it) {
        // ---- forward: carry-producing sums FIRST; shfls issued early,
        //      latency hidden under the sAA/sAB chains. B-chains split 2x10.
        float sBA = 0.f, sBB0 = 0.f, sBB1 = 0.f;
#pragma unroll
        for (int i = 0; i < SA; ++i) sBA = fmaf(spA[i], w2A[i], sBA);
#pragma unroll
        for (int i = 0; i < SB/2; ++i) sBB0 = fmaf(spB[i], w2B[i], sBB0);
#pragma unroll
        for (int i = SB/2; i < SB; ++i) sBB1 = fmaf(spB[i], w2B[i], sBB1);
        const float sBB = sBB0 + sBB1;
        float cAin = __shfl_up(sBA, 1);
        float cBin = __shfl_down(sBB, 1);

        float sAA = 0.f, sAB0 = 0.f, sAB1 = 0.f;
#pragma unroll
        for (int i = 0; i < SA; ++i) sAA = fmaf(spA[i], w1A[i], sAA);
#pragma unroll
        for (int i = 0; i < SB/2; ++i) sAB0 = fmaf(spB[i], w1B[i], sAB0);
#pragma unroll
        for (int i = SB/2; i < SB; ++i) sAB1 = fmaf(spB[i], w1B[i], sAB1);
        const float sAB = sAB0 + sAB1;

        if (lane == 0)  cAin = 0.f;
        if (lane == 63) cBin = sBA;
        const float d0 = m0 - (sAA + cAin);
        const float d1 = m1 - (sAB + cBin);

        // ---- per-lane loss partial: no reduction here (was 6 dependent
        //      DS rounds/iter); scan_reduce does the 64-way sum.
        if (!mode) { bpL[0] = fmaf(d0, d0, d1*d1); bpL += NROWS*64; }

        // ---- backward; dAn/dBn latency hidden under momentum decay
        float dAn = __shfl_down(d0, 1);
        float dBn = __shfl_up(d1, 1);        // lane0: its w2B are all 0
        const float g0 = GC * d0, g1 = GC * d1;
#pragma unroll
        for (int i = 0; i < SA; ++i) bfA[i] *= 0.9f;   // indep of shfls
#pragma unroll
        for (int i = 0; i < SB; ++i) bfB[i] *= 0.9f;
        if (lane == 63) dAn = d1;
        const float gA = GC * dAn, gB = GC * dBn;
#pragma unroll
        for (int i = 0; i < SA; ++i) {
            float g = fmaf(g0, w1A[i], gA * w2A[i]);
            bfA[i] += g;
            float v = fmaf(-0.1f, bfA[i], spA[i]);
            spA[i] = v < 0.f ? 0.f : v;
        }
#pragma unroll
        for (int i = 0; i < SB; ++i) {
            float g = fmaf(g1, w1B[i], gB * w2B[i]);
            bfB[i] += g;
            float v = fmaf(-0.1f, bfB[i], spB[i]);
            spB[i] = v < 0.f ? 0.f : v;
        }
    }

    // ---- store out[batch, f, t] (one-time scatter; L2 merges lines)
    float* og = out + ((size_t)batch*NSTFT)*TIME + t;
#pragma unroll
    for (int i = 0; i < SA; ++i)
        if (i < hA.y) og[(size_t)(hA.x + i)*TIME] = spA[i];
#pragma unroll
    for (int i = 0; i < SB; ++i)
        if (i < hB.y) og[(size_t)(hB.x + i)*TIME] = spB[i];
}

// ---- scan_reduce: block per iteration, 131072 floats -> losses[it] ----
__global__ __launch_bounds__(1024) void scan_reduce(char* __restrict__ ws) {
    __shared__ float wsum[16];
    const int it = blockIdx.x, tid = threadIdx.x;
    const int wave = tid >> 6, lane = tid & 63;
    const float4* b4 = (const float4*)((const float*)(ws + WS_BP_OFF)
                                       + (size_t)it*NROWS*64);
    float s = 0.f;
#pragma unroll
    for (int j = 0; j < 32; ++j) {               // 32768 float4 / 1024 thr
        float4 v = b4[tid + j*1024];
        s += (v.x + v.y) + (v.z + v.w);
    }
#pragma unroll
    for (int m = 32; m; m >>= 1) s += __shfl_xor(s, m);
    if (lane == 0) wsum[wave] = s;
    __syncthreads();
    if (wave == 0) {
        float v = (lane < 16) ? wsum[lane] : 0.f;
#pragma unroll
        for (int m = 8; m; m >>= 1) v += __shfl_xor(v, m);
        if (lane == 0)
            ((float*)(ws + WS_L_OFF))[it] = v * (1.0f/(float)NROWS);
    }
}

extern "C" void kernel_launch(void* const* d_in, const int* in_sizes, int n_in,
                              void* d_out, int out_size, void* d_ws, size_t ws_size,
                              hipStream_t stream)
{
    const float* barkspec  = (const float*)d_in[0];
    const float* fb        = (const float*)d_in[1];
    const float* spec_init = (const float*)d_in[2];
    float* out = (float*)d_out;
    char* ws = (char*)d_ws;

    setup_taps <<<NSTFT, 64, 0, stream>>>(fb, ws);
    setup_lanes<<<NBARK, 64, 0, stream>>>(ws);
    iter_kernel<<<NROWS, 64, 0, stream>>>(barkspec, spec_init, out, ws, 0);
    scan_reduce<<<MAXIT, 1024, 0, stream>>>(ws);
    iter_kernel<<<NROWS, 64, 0, stream>>>(barkspec, spec_init, out, ws, 1);
}

// Round 12
// 108.904 us; speedup vs baseline: 1.5646x; 1.0033x over previous
//
#include <hip/hip_runtime.h>

// InverseBarkScale: 30-iter SGD with momentum inverting a bark filterbank.
// fb (513x128): freq f has taps only at columns (k1(f), k1(f)+1); k1 is
// monotone in f, so P(c) = {f : k1(f)=c} are contiguous and partition
// [0,513). |P(c)| <= ~4 for c<64, <= ~18 for c>=64.
//
// R12: cycle model (closed against R8's 38us iter): per-wave/iter ~350
// issue cyc + exposed DS latency; R8 = 6-round serial loss reduce (~720)
// + TWO dependent main shfl rounds (~240). R11 removed the loss reduce
// (per-lane store + scan_reduce) but kept 2 main rounds. This round: ONE
// shfl round via algebra -- the backward neighbor diffs need only
// PRE-CARRY values plus lane-local terms:
//   dAn(l) = d0(l+1) = u0(l+1) - sBA(l),  u0 = m0 - sAA   (sBA local!)
//   dBn(l) = d1(l-1) = u1(l-1) - sBB(l),  u1 = m1 - sAB   (sBB local!)
// so all 4 shfls (sBA up, sBB down, u0 down, u1 up) issue together in one
// independent round, waited once, hidden under the momentum-decay muls.
// Fixups (all lane-local): lane0 cAin=0, dBn garbage-but-finite (w2B==0);
// lane63 cBin=sBA, dAn=d1.
// Structure: R8/R11 -- all-register iter (lane owns cols l,127-l + their
// primary freqs), per-lane loss store -> 30-block scan_reduce -> repair
// computes S inline and exits immediately when S==30 (true for this data).
// Setup: multi-block ballot kernels (single-block fused setup = 41us
// latency chain, R5-R7 lesson).

#define NSTFT 513
#define NBARK 128
#define BATCH 4
#define TIME  512
#define MAXIT 30
#define NROWS (BATCH*TIME)      // 2048 rows, 1 wave each
#define SA 6                    // A-side slots (cols 0..63, max ~4 real)
#define SB 20                   // B-side slots (cols 64..127, max ~18 real)

// d_ws layout (bytes); ~15.8 MB used. Every field written before read.
#define WS_L_OFF   16                         // float[MAXIT]: losses
#define WS_FT_OFF  256                        // float4[NSTFT]: {k1,w1,-,w2}
#define WS_HA_OFF  8464                       // int2[64]: A {fbase,cnt}
#define WS_HB_OFF  8976                       // int2[64]: B {fbase,cnt}
#define WS_WT_OFF  9488                       // float2[SA+SB][64]: {w1,w2}
#define WS_BP_OFF  22848                      // float[MAXIT][NROWS][64]

// ---- setup 1: per-freq taps, one wave per freq (1 load-round) ----
__global__ __launch_bounds__(64) void setup_taps(const float* __restrict__ fb,
                                                 char* __restrict__ ws) {
    const int f = blockIdx.x, lane = threadIdx.x;
    const float2 v = ((const float2*)(fb + (size_t)f * NBARK))[lane];
    unsigned long long mx = __ballot(v.x > 0.f);
    unsigned long long my = __ballot(v.y > 0.f);
    int kx = mx ? 2 * (__ffsll(mx) - 1)     : 999;
    int ky = my ? 2 * (__ffsll(my) - 1) + 1 : 999;
    int k1 = min(kx, ky);
    float w1 = 0.f, w2 = 0.f;
    if (k1 < NBARK) {
        float sx = __shfl(v.x, k1 >> 1);
        float sy = __shfl(v.y, k1 >> 1);
        w1 = (k1 & 1) ? sy : sx;
        const int k2 = k1 + 1;                   // taps are consecutive cols
        if (k2 < NBARK) {
            float tx = __shfl(v.x, k2 >> 1);
            float ty = __shfl(v.y, k2 >> 1);
            w2 = (k2 & 1) ? ty : tx;             // ==0 if row has 1 tap
        }
    } else {
        k1 = (f < 256) ? 0 : 127;                // all-zero row: edge attach
    }
    if (lane == 0) {
        float4 e;
        e.x = __int_as_float(k1); e.y = w1;
        e.z = 0.f;                e.w = w2;
        ((float4*)(ws + WS_FT_OFF))[f] = e;
    }
}

// ---- setup 2: per-column headers + packed weights, one wave per column ----
__global__ __launch_bounds__(64) void setup_lanes(char* __restrict__ ws) {
    const int c = blockIdx.x, lane = threadIdx.x;
    const float4* ftab = (const float4*)(ws + WS_FT_OFF);
    int fmin = 0x7fffffff, fmax = -1;
#pragma unroll
    for (int s = 0; s < 9; ++s) {
        int f = lane + 64*s;
        if (f < NSTFT) {
            float4 e = ftab[f];
            if (__float_as_int(e.x) == c) { fmin = min(fmin, f); fmax = max(fmax, f); }
        }
    }
#pragma unroll
    for (int m = 32; m; m >>= 1) {
        fmin = min(fmin, __shfl_xor(fmin, m));
        fmax = max(fmax, __shfl_xor(fmax, m));
    }
    int cnt = (fmax >= 0) ? (fmax - fmin + 1) : 0;
    if (fmax < 0) fmin = 0;
    const int cap  = (c < 64) ? SA : SB;
    const int base = (c < 64) ? 0  : SA;
    const int lf   = (c < 64) ? c  : 127 - c;
    cnt = min(cnt, cap);
    if (lane == 0)
        ((int2*)(ws + (c < 64 ? WS_HA_OFF : WS_HB_OFF)))[lf] =
            make_int2(fmin, cnt);
    if (lane < cap) {
        float2 wv = make_float2(0.f, 0.f);
        if (lane < cnt) {
            float4 e = ftab[fmin + lane];        // L2-hit re-read, tiny
            wv = make_float2(e.y, e.w);
        }
        ((float2*)(ws + WS_WT_OFF))[(base + lane)*64 + lf] = wv;
    }
}

__global__ __launch_bounds__(64, 2) void
iter_kernel(const float* __restrict__ barkspec,
            const float* __restrict__ spec_init,
            float* __restrict__ out,
            char* __restrict__ ws, int mode)
{
    const int lane = threadIdx.x;            // single wave per block, no LDS

    int niter = MAXIT;
    if (mode) {
        // reference stop logic from losses[]: update applied on the stop
        // iteration, frozen after -> S = first stop index + 1, else MAXIT
        const float* losses = (const float*)(ws + WS_L_OFF);
        float prev = __builtin_inff();
        int S = MAXIT;
        for (int i = 0; i < MAXIT; ++i) {
            float l = losses[i];
            if (l < 1e-5f || fabsf(prev - l) < 1e-8f) { S = i + 1; break; }
            prev = l;
        }
        if (S >= MAXIT) return;              // expected path: no repair
        niter = S;
    }

    const int r     = blockIdx.x;
    const int batch = r >> 9;
    const int t     = r & (TIME - 1);

    // ---- per-lane tables -> registers ----
    const int2 hA = ((const int2*)(ws + WS_HA_OFF))[lane];
    const int2 hB = ((const int2*)(ws + WS_HB_OFF))[lane];
    const float2* wt = (const float2*)(ws + WS_WT_OFF);
    const float* spg = spec_init + ((size_t)batch*TIME + t)*NSTFT;

    float w1A[SA], w2A[SA], spA[SA], bfA[SA];
    float w1B[SB], w2B[SB], spB[SB], bfB[SB];
#pragma unroll
    for (int i = 0; i < SA; ++i) {
        float2 v = wt[i*64 + lane];
        w1A[i] = v.x; w2A[i] = v.y;
        spA[i] = (i < hA.y) ? spg[hA.x + i] : 0.f;
        bfA[i] = 0.f;
    }
#pragma unroll
    for (int i = 0; i < SB; ++i) {
        float2 v = wt[(SA + i)*64 + lane];
        w1B[i] = v.x; w2B[i] = v.y;
        spB[i] = (i < hB.y) ? spg[hB.x + i] : 0.f;
        bfB[i] = 0.f;
    }

    const float* bs = barkspec + (size_t)batch*NBARK*TIME + t;
    const float m0 = bs[(size_t)lane*TIME];          // col cA = lane
    const float m1 = bs[(size_t)(127 - lane)*TIME];  // col cB = 127-lane

    // per-lane loss partial store target (256B coalesced per wave)
    float* bpL = (float*)(ws + WS_BP_OFF) + (size_t)r*64 + lane;
    const float GC = -2.0f / (float)NROWS;

    for (int it = 0; it < niter; ++it) {
        // ---- forward: all 4 per-lane sums (B chains split 2x10)
        float sBA = 0.f, sBB0 = 0.f, sBB1 = 0.f;
#pragma unroll
        for (int i = 0; i < SA; ++i) sBA = fmaf(spA[i], w2A[i], sBA);
#pragma unroll
        for (int i = 0; i < SB/2; ++i) sBB0 = fmaf(spB[i], w2B[i], sBB0);
#pragma unroll
        for (int i = SB/2; i < SB; ++i) sBB1 = fmaf(spB[i], w2B[i], sBB1);
        float sAA = 0.f, sAB0 = 0.f, sAB1 = 0.f;
#pragma unroll
        for (int i = 0; i < SA; ++i) sAA = fmaf(spA[i], w1A[i], sAA);
#pragma unroll
        for (int i = 0; i < SB/2; ++i) sAB0 = fmaf(spB[i], w1B[i], sAB0);
#pragma unroll
        for (int i = SB/2; i < SB; ++i) sAB1 = fmaf(spB[i], w1B[i], sAB1);
        const float sBB = sBB0 + sBB1;
        const float u0  = m0 - sAA;
        const float u1  = m1 - (sAB0 + sAB1);

        // ---- SINGLE shfl round: all 4 independent, waited once
        float a = __shfl_up(sBA, 1);         // carry into column l
        float b = __shfl_down(sBB, 1);       // carry into column 127-l
        float p = __shfl_down(u0, 1);        // u0(l+1)
        float q = __shfl_up(u1, 1);          // u1(l-1)

        // ---- hide the DS wait under momentum decay (independent)
#pragma unroll
        for (int i = 0; i < SA; ++i) bfA[i] *= 0.9f;
#pragma unroll
        for (int i = 0; i < SB; ++i) bfB[i] *= 0.9f;

        // ---- diffs + neighbor diffs, lane-local fixups
        if (lane == 0)  a = 0.f;
        if (lane == 63) b = sBA;
        const float d0 = u0 - a;
        const float d1 = u1 - b;
        float dAn = p - sBA;                 // d0(l+1) = u0(l+1) - sBA(l)
        if (lane == 63) dAn = d1;            // column 64 = lane63's B-col
        const float dBn = q - sBB;           // d1(l-1); lane0: w2B==0 anyway

        if (!mode) { bpL[0] = fmaf(d0, d0, d1*d1); bpL += NROWS*64; }

        // ---- SGD update
        const float g0 = GC * d0, g1 = GC * d1;
        const float gA = GC * dAn, gB = GC * dBn;
#pragma unroll
        for (int i = 0; i < SA; ++i) {
            float g = fmaf(g0, w1A[i], gA * w2A[i]);
            bfA[i] += g;
            float v = fmaf(-0.1f, bfA[i], spA[i]);
            spA[i] = v < 0.f ? 0.f : v;
        }
#pragma unroll
        for (int i = 0; i < SB; ++i) {
            float g = fmaf(g1, w1B[i], gB * w2B[i]);
            bfB[i] += g;
            float v = fmaf(-0.1f, bfB[i], spB[i]);
            spB[i] = v < 0.f ? 0.f : v;
        }
    }

    // ---- store out[batch, f, t] (one-time scatter; L2 merges lines)
    float* og = out + ((size_t)batch*NSTFT)*TIME + t;
#pragma unroll
    for (int i = 0; i < SA; ++i)
        if (i < hA.y) og[(size_t)(hA.x + i)*TIME] = spA[i];
#pragma unroll
    for (int i = 0; i < SB; ++i)
        if (i < hB.y) og[(size_t)(hB.x + i)*TIME] = spB[i];
}

// ---- scan_reduce: block per iteration, 131072 floats -> losses[it] ----
__global__ __launch_bounds__(1024) void scan_reduce(char* __restrict__ ws) {
    __shared__ float wsum[16];
    const int it = blockIdx.x, tid = threadIdx.x;
    const int wave = tid >> 6, lane = tid & 63;
    const float4* b4 = (const float4*)((const float*)(ws + WS_BP_OFF)
                                       + (size_t)it*NROWS*64);
    float s = 0.f;
#pragma unroll
    for (int j = 0; j < 32; ++j) {               // 32768 float4 / 1024 thr
        float4 v = b4[tid + j*1024];
        s += (v.x + v.y) + (v.z + v.w);
    }
#pragma unroll
    for (int m = 32; m; m >>= 1) s += __shfl_xor(s, m);
    if (lane == 0) wsum[wave] = s;
    __syncthreads();
    if (wave == 0) {
        float v = (lane < 16) ? wsum[lane] : 0.f;
#pragma unroll
        for (int m = 8; m; m >>= 1) v += __shfl_xor(v, m);
        if (lane == 0)
            ((float*)(ws + WS_L_OFF))[it] = v * (1.0f/(float)NROWS);
    }
}

extern "C" void kernel_launch(void* const* d_in, const int* in_sizes, int n_in,
                              void* d_out, int out_size, void* d_ws, size_t ws_size,
                              hipStream_t stream)
{
    const float* barkspec  = (const float*)d_in[0];
    const float* fb        = (const float*)d_in[1];
    const float* spec_init = (const float*)d_in[2];
    float* out = (float*)d_out;
    char* ws = (char*)d_ws;

    setup_taps <<<NSTFT, 64, 0, stream>>>(fb, ws);
    setup_lanes<<<NBARK, 64, 0, stream>>>(ws);
    iter_kernel<<<NROWS, 64, 0, stream>>>(barkspec, spec_init, out, ws, 0);
    scan_reduce<<<MAXIT, 1024, 0, stream>>>(ws);
    iter_kernel<<<NROWS, 64, 0, stream>>>(barkspec, spec_init, out, ws, 1);
}

// Round 13
// 108.478 us; speedup vs baseline: 1.5707x; 1.0039x over previous
//
#include <hip/hip_runtime.h>

// InverseBarkScale: 30-iter SGD with momentum inverting a bark filterbank.
// fb (513x128): freq f has taps only at columns (k1(f), k1(f)+1); k1 is
// monotone in f, so P(c) = {f : k1(f)=c} are contiguous and partition
// [0,513). |P(c)| <= ~4 for c<64, <= ~18 for c>=64.
//
// R13: occupancy is GRID-limited (2048 rows x 1 wave = 2 waves/SIMD) and
// iter sits at ~36us vs an ~8.5us issue floor (VALUBusy ~45%). TLP can't
// grow -> grow ILP: TWO ROWS PER WAVE (r0=2b, r1=2b+1). Filter tables are
// lane-indexed -> shared between rows (52 VGPR); only state duplicates
// (~200 VGPR, launch_bounds(64,1)). The 8 shfls (4/row) issue as one batch,
// waited once, hidden under the other row's FMA stream + 52 decay muls.
// Adjacent-t pairing makes the strided m/out/spec accesses share cache
// lines (halves line dispersion). 1024 blocks = 1 wave/SIMD, issue-bound
// ~900cyc/iter/SIMD -> iter ~16us predicted.
// Structure: speculate 30 iters + per-lane loss store -> 30-block
// scan_reduce -> repair computes S inline, exits immediately (S==30 on
// this data; R6's "42us repair" rows were mode0 rows from a second PMC
// replay pass -- WRITE_SIZE=NaN tell).
// Setup: multi-block ballot kernels (single-block fused setup = 41us
// one-CU latency chain, R5-R7 lesson).

#define NSTFT 513
#define NBARK 128
#define BATCH 4
#define TIME  512
#define MAXIT 30
#define NROWS (BATCH*TIME)      // 2048 rows, 2 per wave
#define SA 6                    // A-side slots (cols 0..63, max ~4 real)
#define SB 20                   // B-side slots (cols 64..127, max ~18 real)

// d_ws layout (bytes); ~15.8 MB used. Every field written before read.
#define WS_L_OFF   16                         // float[MAXIT]: losses
#define WS_FT_OFF  256                        // float4[NSTFT]: {k1,w1,-,w2}
#define WS_HA_OFF  8464                       // int2[64]: A {fbase,cnt}
#define WS_HB_OFF  8976                       // int2[64]: B {fbase,cnt}
#define WS_WT_OFF  9488                       // float2[SA+SB][64]: {w1,w2}
#define WS_BP_OFF  22848                      // float[MAXIT][NROWS][64]

// ---- setup 1: per-freq taps, one wave per freq (1 load-round) ----
__global__ __launch_bounds__(64) void setup_taps(const float* __restrict__ fb,
                                                 char* __restrict__ ws) {
    const int f = blockIdx.x, lane = threadIdx.x;
    const float2 v = ((const float2*)(fb + (size_t)f * NBARK))[lane];
    unsigned long long mx = __ballot(v.x > 0.f);
    unsigned long long my = __ballot(v.y > 0.f);
    int kx = mx ? 2 * (__ffsll(mx) - 1)     : 999;
    int ky = my ? 2 * (__ffsll(my) - 1) + 1 : 999;
    int k1 = min(kx, ky);
    float w1 = 0.f, w2 = 0.f;
    if (k1 < NBARK) {
        float sx = __shfl(v.x, k1 >> 1);
        float sy = __shfl(v.y, k1 >> 1);
        w1 = (k1 & 1) ? sy : sx;
        const int k2 = k1 + 1;                   // taps are consecutive cols
        if (k2 < NBARK) {
            float tx = __shfl(v.x, k2 >> 1);
            float ty = __shfl(v.y, k2 >> 1);
            w2 = (k2 & 1) ? ty : tx;             // ==0 if row has 1 tap
        }
    } else {
        k1 = (f < 256) ? 0 : 127;                // all-zero row: edge attach
    }
    if (lane == 0) {
        float4 e;
        e.x = __int_as_float(k1); e.y = w1;
        e.z = 0.f;                e.w = w2;
        ((float4*)(ws + WS_FT_OFF))[f] = e;
    }
}

// ---- setup 2: per-column headers + packed weights, one wave per column ----
__global__ __launch_bounds__(64) void setup_lanes(char* __restrict__ ws) {
    const int c = blockIdx.x, lane = threadIdx.x;
    const float4* ftab = (const float4*)(ws + WS_FT_OFF);
    int fmin = 0x7fffffff, fmax = -1;
#pragma unroll
    for (int s = 0; s < 9; ++s) {
        int f = lane + 64*s;
        if (f < NSTFT) {
            float4 e = ftab[f];
            if (__float_as_int(e.x) == c) { fmin = min(fmin, f); fmax = max(fmax, f); }
        }
    }
#pragma unroll
    for (int m = 32; m; m >>= 1) {
        fmin = min(fmin, __shfl_xor(fmin, m));
        fmax = max(fmax, __shfl_xor(fmax, m));
    }
    int cnt = (fmax >= 0) ? (fmax - fmin + 1) : 0;
    if (fmax < 0) fmin = 0;
    const int cap  = (c < 64) ? SA : SB;
    const int base = (c < 64) ? 0  : SA;
    const int lf   = (c < 64) ? c  : 127 - c;
    cnt = min(cnt, cap);
    if (lane == 0)
        ((int2*)(ws + (c < 64 ? WS_HA_OFF : WS_HB_OFF)))[lf] =
            make_int2(fmin, cnt);
    if (lane < cap) {
        float2 wv = make_float2(0.f, 0.f);
        if (lane < cnt) {
            float4 e = ftab[fmin + lane];        // L2-hit re-read, tiny
            wv = make_float2(e.y, e.w);
        }
        ((float2*)(ws + WS_WT_OFF))[(base + lane)*64 + lf] = wv;
    }
}

__global__ __launch_bounds__(64, 1) void
iter_kernel(const float* __restrict__ barkspec,
            const float* __restrict__ spec_init,
            float* __restrict__ out,
            char* __restrict__ ws, int mode)
{
    const int lane = threadIdx.x;            // single wave, TWO rows

    int niter = MAXIT;
    if (mode) {
        // reference stop logic from losses[]: update applied on the stop
        // iteration, frozen after -> S = first stop index + 1, else MAXIT
        const float* losses = (const float*)(ws + WS_L_OFF);
        float prev = __builtin_inff();
        int S = MAXIT;
        for (int i = 0; i < MAXIT; ++i) {
            float l = losses[i];
            if (l < 1e-5f || fabsf(prev - l) < 1e-8f) { S = i + 1; break; }
            prev = l;
        }
        if (S >= MAXIT) return;              // expected path: no repair
        niter = S;
    }

    const int r0    = blockIdx.x * 2;        // rows r0, r0+1 (same batch,
    const int batch = r0 >> 9;               //  adjacent t -> shared lines)
    const int t0    = r0 & (TIME - 1);

    // ---- shared per-lane tables -> registers (lane-indexed: both rows) --
    const int2 hA = ((const int2*)(ws + WS_HA_OFF))[lane];
    const int2 hB = ((const int2*)(ws + WS_HB_OFF))[lane];
    const float2* wt = (const float2*)(ws + WS_WT_OFF);
    const float* spg = spec_init + ((size_t)batch*TIME + t0)*NSTFT;

    float w1A[SA], w2A[SA], w1B[SB], w2B[SB];
    float spA[2][SA], bfA[2][SA], spB[2][SB], bfB[2][SB];
#pragma unroll
    for (int i = 0; i < SA; ++i) {
        float2 v = wt[i*64 + lane];
        w1A[i] = v.x; w2A[i] = v.y;
        spA[0][i] = (i < hA.y) ? spg[hA.x + i] : 0.f;
        spA[1][i] = (i < hA.y) ? spg[NSTFT + hA.x + i] : 0.f;
        bfA[0][i] = 0.f; bfA[1][i] = 0.f;
    }
#pragma unroll
    for (int i = 0; i < SB; ++i) {
        float2 v = wt[(SA + i)*64 + lane];
        w1B[i] = v.x; w2B[i] = v.y;
        spB[0][i] = (i < hB.y) ? spg[hB.x + i] : 0.f;
        spB[1][i] = (i < hB.y) ? spg[NSTFT + hB.x + i] : 0.f;
        bfB[0][i] = 0.f; bfB[1][i] = 0.f;
    }

    const float* bs = barkspec + (size_t)batch*NBARK*TIME + t0;
    const float m0[2] = { bs[(size_t)lane*TIME],
                          bs[(size_t)lane*TIME + 1] };
    const float m1[2] = { bs[(size_t)(127 - lane)*TIME],
                          bs[(size_t)(127 - lane)*TIME + 1] };

    float* bp = (float*)(ws + WS_BP_OFF) + (size_t)r0*64 + lane;
    const float GC = -2.0f / (float)NROWS;

    for (int it = 0; it < niter; ++it) {
        float d0[2], d1[2], dAn[2], dBn[2];
        float sBA[2], sBB[2], u0[2], u1[2];
        // ---- forward: per-lane sums, both rows interleaved (indep chains)
#pragma unroll
        for (int x = 0; x < 2; ++x) {
            float a = 0.f, b0 = 0.f, b1 = 0.f, c = 0.f, e0 = 0.f, e1 = 0.f;
#pragma unroll
            for (int i = 0; i < SA; ++i) {
                a = fmaf(spA[x][i], w2A[i], a);
                c = fmaf(spA[x][i], w1A[i], c);
            }
#pragma unroll
            for (int i = 0; i < SB/2; ++i) {
                b0 = fmaf(spB[x][i], w2B[i], b0);
                e0 = fmaf(spB[x][i], w1B[i], e0);
            }
#pragma unroll
            for (int i = SB/2; i < SB; ++i) {
                b1 = fmaf(spB[x][i], w2B[i], b1);
                e1 = fmaf(spB[x][i], w1B[i], e1);
            }
            sBA[x] = a; sBB[x] = b0 + b1;
            u0[x] = m0[x] - c; u1[x] = m1[x] - (e0 + e1);
        }

        // ---- ONE shfl batch (8 independent), waited once
        float sa[2], sb[2], sp_[2], sq[2];
#pragma unroll
        for (int x = 0; x < 2; ++x) {
            sa[x] = __shfl_up(sBA[x], 1);    // carry into column l
            sb[x] = __shfl_down(sBB[x], 1);  // carry into column 127-l
            sp_[x] = __shfl_down(u0[x], 1);  // u0(l+1)
            sq[x] = __shfl_up(u1[x], 1);     // u1(l-1)
        }

        // ---- hide the DS wait under momentum decay (independent)
#pragma unroll
        for (int x = 0; x < 2; ++x) {
#pragma unroll
            for (int i = 0; i < SA; ++i) bfA[x][i] *= 0.9f;
#pragma unroll
            for (int i = 0; i < SB; ++i) bfB[x][i] *= 0.9f;
        }

        // ---- diffs + neighbor diffs, lane-local fixups
#pragma unroll
        for (int x = 0; x < 2; ++x) {
            float a = sa[x], b = sb[x];
            if (lane == 0)  a = 0.f;
            if (lane == 63) b = sBA[x];
            d0[x] = u0[x] - a;
            d1[x] = u1[x] - b;
            float dn = sp_[x] - sBA[x];      // d0(l+1) = u0(l+1) - sBA(l)
            if (lane == 63) dn = d1[x];      // column 64 = lane63's B-col
            dAn[x] = dn;
            dBn[x] = sq[x] - sBB[x];         // d1(l-1); lane0: w2B==0
        }

        if (!mode) {
            bp[0]  = fmaf(d0[0], d0[0], d1[0]*d1[0]);
            bp[64] = fmaf(d0[1], d0[1], d1[1]*d1[1]);
            bp += NROWS*64;
        }

        // ---- SGD update (both rows)
#pragma unroll
        for (int x = 0; x < 2; ++x) {
            const float g0 = GC * d0[x], g1 = GC * d1[x];
            const float gA = GC * dAn[x], gB = GC * dBn[x];
#pragma unroll
            for (int i = 0; i < SA; ++i) {
                float g = fmaf(g0, w1A[i], gA * w2A[i]);
                bfA[x][i] += g;
                float v = fmaf(-0.1f, bfA[x][i], spA[x][i]);
                spA[x][i] = v < 0.f ? 0.f : v;
            }
#pragma unroll
            for (int i = 0; i < SB; ++i) {
                float g = fmaf(g1, w1B[i], gB * w2B[i]);
                bfB[x][i] += g;
                float v = fmaf(-0.1f, bfB[x][i], spB[x][i]);
                spB[x][i] = v < 0.f ? 0.f : v;
            }
        }
    }

    // ---- store out[batch, f, t0/t0+1] (adjacent t -> shared lines)
    float* og = out + ((size_t)batch*NSTFT)*TIME + t0;
#pragma unroll
    for (int i = 0; i < SA; ++i)
        if (i < hA.y) {
            og[(size_t)(hA.x + i)*TIME]     = spA[0][i];
            og[(size_t)(hA.x + i)*TIME + 1] = spA[1][i];
        }
#pragma unroll
    for (int i = 0; i < SB; ++i)
        if (i < hB.y) {
            og[(size_t)(hB.x + i)*TIME]     = spB[0][i];
            og[(size_t)(hB.x + i)*TIME + 1] = spB[1][i];
        }
}

// ---- scan_reduce: block per iteration, 131072 floats -> losses[it] ----
__global__ __launch_bounds__(1024) void scan_reduce(char* __restrict__ ws) {
    __shared__ float wsum[16];
    const int it = blockIdx.x, tid = threadIdx.x;
    const int wave = tid >> 6, lane = tid & 63;
    const float4* b4 = (const float4*)((const float*)(ws + WS_BP_OFF)
                                       + (size_t)it*NROWS*64);
    float s = 0.f;
#pragma unroll
    for (int j = 0; j < 32; ++j) {               // 32768 float4 / 1024 thr
        float4 v = b4[tid + j*1024];
        s += (v.x + v.y) + (v.z + v.w);
    }
#pragma unroll
    for (int m = 32; m; m >>= 1) s += __shfl_xor(s, m);
    if (lane == 0) wsum[wave] = s;
    __syncthreads();
    if (wave == 0) {
        float v = (lane < 16) ? wsum[lane] : 0.f;
#pragma unroll
        for (int m = 8; m; m >>= 1) v += __shfl_xor(v, m);
        if (lane == 0)
            ((float*)(ws + WS_L_OFF))[it] = v * (1.0f/(float)NROWS);
    }
}

extern "C" void kernel_launch(void* const* d_in, const int* in_sizes, int n_in,
                              void* d_out, int out_size, void* d_ws, size_t ws_size,
                              hipStream_t stream)
{
    const float* barkspec  = (const float*)d_in[0];
    const float* fb        = (const float*)d_in[1];
    const float* spec_init = (const float*)d_in[2];
    float* out = (float*)d_out;
    char* ws = (char*)d_ws;

    setup_taps <<<NSTFT, 64, 0, stream>>>(fb, ws);
    setup_lanes<<<NBARK, 64, 0, stream>>>(ws);
    iter_kernel<<<NROWS/2, 64, 0, stream>>>(barkspec, spec_init, out, ws, 0);
    scan_reduce<<<MAXIT, 1024, 0, stream>>>(ws);
    iter_kernel<<<NROWS/2, 64, 0, stream>>>(barkspec, spec_init, out, ws, 1);
}